// Round 18
// baseline (4592.321 us; speedup 1.0000x reference)
//
#include <hip/hip_runtime.h>
#include <hip/hip_bf16.h>

typedef unsigned short u16;
typedef unsigned int u32;

#define NN 131072   // nodes
#define NE 262144   // edges
#define NG 4096     // graphs
#define EMB 300
#define HID 600
#define NL 5
#define NTNE 96     // N_TASKS * N_EXPERTS
#define NEXP 8

// weight-transpose layouts (k-contiguous, padded)
#define W1T_ROWS 640
#define W1T_K    328
#define W2T_ROWS 384
#define W2T_K    648
#define EE_S     304   // ee table row stride (u16)
#define AF_S     324   // fp32 LDS accumulator row stride (floats; 16B-aligned rows)

typedef __attribute__((ext_vector_type(8)))  short  s16x8;
typedef __attribute__((ext_vector_type(8)))  __bf16 b16x8;
typedef __attribute__((ext_vector_type(16))) float  f32x16;

static __device__ __forceinline__ float u2f(u16 u) {
    union { u32 i; float f; } w; w.i = ((u32)u) << 16; return w.f;
}
static __device__ __forceinline__ u16 f2u(float f) {
    union { float f; u32 i; } w; w.f = f;
    return (u16)((w.i + 0x7fffu + ((w.i >> 16) & 1u)) >> 16);
}

static __device__ __forceinline__ f32x16 mfma_3216(s16x8 a, s16x8 b, f32x16 c) {
    return __builtin_amdgcn_mfma_f32_32x32x16_bf16(
        __builtin_bit_cast(b16x8, a), __builtin_bit_cast(b16x8, b), c, 0, 0, 0);
}

// ---------------- zero fill ----------------
__global__ void k_zero(float* __restrict__ p, int n) {
    int i = blockIdx.x * 256 + threadIdx.x;
    if (i < n) p[i] = 0.f;
}
__global__ void k_zero_int(int* __restrict__ p, int n) {
    int i = blockIdx.x * 256 + threadIdx.x;
    if (i < n) p[i] = 0;
}

// ---------------- embedding ----------------
__global__ void k_embed(const int* __restrict__ x, const float* __restrict__ ae1,
                        const float* __restrict__ ae2, u16* __restrict__ h) {
    int i = blockIdx.x;
    int a0 = x[2 * i], a1 = x[2 * i + 1];
    for (int f = threadIdx.x; f < EMB; f += blockDim.x)
        h[(size_t)i * EMB + f] = f2u(ae1[a0 * EMB + f] + ae2[a1 * EMB + f]);
}

// ---------------- CSR build ----------------
__global__ void k_hist(const int* __restrict__ ei, int* __restrict__ deg) {
    int e = blockIdx.x * 256 + threadIdx.x;
    if (e < NE) atomicAdd(&deg[ei[NE + e]], 1);
}

__global__ __launch_bounds__(1024) void k_scan(const int* __restrict__ deg,
                                               int* __restrict__ rowstart) {
    __shared__ int lds[1024];
    int tid = threadIdx.x;
    int base = tid * 128;   // 1024 * 128 = 131072
    int s = 0;
    for (int j = 0; j < 128; ++j) s += deg[base + j];
    lds[tid] = s;
    __syncthreads();
    for (int off = 1; off < 1024; off <<= 1) {
        int v = (tid >= off) ? lds[tid - off] : 0;
        __syncthreads();
        lds[tid] += v;
        __syncthreads();
    }
    int run = (tid == 0) ? 0 : lds[tid - 1];
    for (int j = 0; j < 128; ++j) {
        rowstart[base + j] = run;
        run += deg[base + j];
    }
    if (tid == 1023) rowstart[NN] = run;
}

// consumes deg as cursor (ends at 0).
// payload = src | combo<<17 | (dst&31)<<22   (rowBase is 32-aligned -> dst&31 = local row)
__global__ void k_fill(const int* __restrict__ ei, const int* __restrict__ ea,
                       int* __restrict__ deg, const int* __restrict__ rowstart,
                       u32* __restrict__ payload) {
    int e = blockIdx.x * 256 + threadIdx.x;
    if (e >= NE) return;
    int src = ei[e], dst = ei[NE + e];
    int c = ea[2 * e] * 3 + ea[2 * e + 1];
    int old = atomicSub(&deg[dst], 1);
    int pos = rowstart[dst] + old - 1;
    payload[pos] = (u32)src | ((u32)c << 17) | ((u32)(dst & 31) << 22);
}

// ---------------- weight pre-transpose (fp32 -> bf16, k-contiguous) ----------------
__global__ void k_prep_w1(const float* __restrict__ w1, u16* __restrict__ w1t) {
    int n = blockIdx.x;
    int l = blockIdx.y;
    size_t dst = ((size_t)l * W1T_ROWS + n) * W1T_K;
    for (int k = threadIdx.x; k < W1T_K; k += blockDim.x) {
        u16 v = 0;
        if (n < HID && k < EMB) v = f2u(w1[(size_t)l * EMB * HID + (size_t)k * HID + n]);
        w1t[dst + k] = v;
    }
}
__global__ void k_prep_w2(const float* __restrict__ w2, u16* __restrict__ w2t) {
    int n = blockIdx.x;
    int l = blockIdx.y;
    size_t dst = ((size_t)l * W2T_ROWS + n) * W2T_K;
    for (int k = threadIdx.x; k < W2T_K; k += blockDim.x) {
        u16 v = 0;
        if (n < EMB && k < HID) v = f2u(w2[(size_t)l * HID * EMB + (size_t)k * EMB + n]);
        w2t[dst + k] = v;
    }
}

// ---------------- ee-combo table (bf16), once per call ----------------
__global__ void k_prep_ee(const float* __restrict__ ee1, const float* __restrict__ ee2,
                          u16* __restrict__ eeT) {
    int c = blockIdx.x;   // 0..17
    int l = blockIdx.y;   // layer
    size_t dst = ((size_t)l * 18 + c) * EE_S;
    const float* e1 = ee1 + (size_t)l * 6 * EMB + (c / 3) * EMB;
    const float* e2 = ee2 + (size_t)l * 3 * EMB + (c % 3) * EMB;
    for (int f = threadIdx.x; f < EE_S; f += blockDim.x)
        eeT[dst + f] = (f < EMB) ? f2u(e1[f] + e2[f]) : (u16)0;
}

// ---------------- BN scale/shift table (bf16), per layer ----------------
__global__ void k_prep_bn(const float* __restrict__ stats, const float* __restrict__ bg,
                          const float* __restrict__ bb, float invM,
                          u16* __restrict__ scT, u16* __restrict__ shT) {
    int t = threadIdx.x;
    if (t >= EE_S) return;
    if (t < EMB) {
        float mu = stats[t] * invM;
        float var = stats[EMB + t] * invM - mu * mu;
        float sc = bg[t] * rsqrtf(var + 1e-5f);
        scT[t] = f2u(sc);
        shT[t] = f2u(bb[t] - mu * sc);
    } else {
        scT[t] = 0; shT[t] = 0;
    }
}

// ---- fused (BN+relu of prev layer) + EDGE-PARALLEL aggregate + GEMM1 ----
// 32 rows/block, 256 threads. Phase A: init fp32 LDS acc with bn(h_self)+self_ee.
// Phase B: (edge x chunk) tasks — block's edges are CSR-contiguous — each task
// does one coalesced 8B h read + 4x ds_add_f32. No dependent edge chains.
// Phase C: fp32->bf16 fragment preload + MFMA. LDS 40.5 KB -> up to 4 blocks/CU.
template <bool APPLY_BN>
__global__ __launch_bounds__(256) void k_layer1(const u16* __restrict__ h,
                                                const u32* __restrict__ payload,
                                                const int* __restrict__ rowstart,
                                                const u16* __restrict__ eeT,
                                                const u16* __restrict__ scT,
                                                const u16* __restrict__ shT,
                                                const u16* __restrict__ w1t,
                                                const float* __restrict__ b1,
                                                u16* __restrict__ hid) {
    __shared__ __align__(16) float Af[32 * AF_S];   // 40.5 KB
    __shared__ int rs_s[33];
    int tid = threadIdx.x;
    int lane = tid & 63, wc = tid >> 6;   // 4 waves = 4 col groups
    int l31 = lane & 31, lhi = lane >> 5;
    size_t rowBase = (size_t)blockIdx.x * 32;

    if (tid < 33) rs_s[tid] = rowstart[rowBase + tid];

    // Phase A: init Af = bn(h_self) + self_ee (fp32), pad cols 300..323 = 0
    for (int task = tid; task < 32 * 81; task += 256) {
        int r = task / 81, q = task - r * 81;
        int f0 = q * 4;
        float v0 = 0.f, v1 = 0.f, v2 = 0.f, v3 = 0.f;
        if (f0 < EMB) {
            int i = (int)rowBase + r;
            ushort4 hv = *(const ushort4*)&h[(size_t)i * EMB + f0];
            ushort4 ev = *(const ushort4*)&eeT[12 * EE_S + f0];  // self combo
            float a0 = u2f(hv.x), a1 = u2f(hv.y), a2 = u2f(hv.z), a3 = u2f(hv.w);
            if (APPLY_BN) {
                ushort4 scv = *(const ushort4*)&scT[f0];
                ushort4 shv = *(const ushort4*)&shT[f0];
                a0 = fmaxf(a0 * u2f(scv.x) + u2f(shv.x), 0.f);
                a1 = fmaxf(a1 * u2f(scv.y) + u2f(shv.y), 0.f);
                a2 = fmaxf(a2 * u2f(scv.z) + u2f(shv.z), 0.f);
                a3 = fmaxf(a3 * u2f(scv.w) + u2f(shv.w), 0.f);
            }
            v0 = a0 + u2f(ev.x); v1 = a1 + u2f(ev.y);
            v2 = a2 + u2f(ev.z); v3 = a3 + u2f(ev.w);
        }
        float4 o = {v0, v1, v2, v3};
        *(float4*)&Af[r * AF_S + f0] = o;
    }
    __syncthreads();

    // Phase B: edge-parallel accumulate
    {
        int eBeg = rs_s[0], eEnd = rs_s[32];
        int nt = (eEnd - eBeg) * 75;
        for (int task = tid; task < nt; task += 256) {
            int ei75 = task / 75;
            int fc = task - ei75 * 75;
            int f0 = fc * 4;
            u32 p = payload[eBeg + ei75];
            int src = p & 0x1FFFF;
            int combo = (p >> 17) & 31;
            int dl = (p >> 22) & 31;
            ushort4 sv = *(const ushort4*)&h[(size_t)src * EMB + f0];
            ushort4 ec = *(const ushort4*)&eeT[(size_t)combo * EE_S + f0];
            float g0 = u2f(sv.x), g1 = u2f(sv.y), g2 = u2f(sv.z), g3 = u2f(sv.w);
            if (APPLY_BN) {
                ushort4 scv = *(const ushort4*)&scT[f0];
                ushort4 shv = *(const ushort4*)&shT[f0];
                g0 = fmaxf(g0 * u2f(scv.x) + u2f(shv.x), 0.f);
                g1 = fmaxf(g1 * u2f(scv.y) + u2f(shv.y), 0.f);
                g2 = fmaxf(g2 * u2f(scv.z) + u2f(shv.z), 0.f);
                g3 = fmaxf(g3 * u2f(scv.w) + u2f(shv.w), 0.f);
            }
            float* ap = &Af[dl * AF_S + f0];
            atomicAdd(&ap[0], g0 + u2f(ec.x));
            atomicAdd(&ap[1], g1 + u2f(ec.y));
            atomicAdd(&ap[2], g2 + u2f(ec.z));
            atomicAdd(&ap[3], g3 + u2f(ec.w));
        }
    }
    __syncthreads();

    // Phase C: preload A fragments (fp32 -> bf16 once), then MFMA
    s16x8 afr[20];
    int abase = l31 * AF_S + lhi * 8;
#pragma unroll
    for (int s = 0; s < 20; ++s) {
        const float* ap = &Af[abase + s * 16];
        s16x8 t;
#pragma unroll
        for (int j = 0; j < 8; ++j) t[j] = (short)f2u(ap[j]);
        afr[s] = t;
    }

    // 5 col-chunks of 128; B direct from w1t (L2)
    for (int c5 = 0; c5 < 5; ++c5) {
        int col = c5 * 128 + wc * 32 + l31;
        const u16* bp = w1t + (size_t)col * W1T_K + lhi * 8;
        f32x16 acc = {};
#pragma unroll
        for (int s = 0; s < 20; ++s)
            acc = mfma_3216(afr[s], *(const s16x8*)&bp[s * 16], acc);
        if (col < HID) {
            float bias = b1[col];
#pragma unroll
            for (int r = 0; r < 16; ++r) {
                int row = (r & 3) + 8 * (r >> 2) + 4 * lhi;
                hid[(rowBase + row) * HID + col] =
                    f2u(fmaxf(acc[r] + bias, 0.f));
            }
        }
    }
}

// ---------------- MFMA GEMM2 (LDS-staged, k-tiled): hbuf = hid @ W2 + b2 --------
// grid (3, NN/64): the 3 col-chunks of a row strip are dispatch-adjacent so the
// hid strip stays L2/L3-hot.
__global__ __launch_bounds__(256) void k_gemm2(const u16* __restrict__ hid,
                                               const u16* __restrict__ w2t,
                                               const float* __restrict__ b2,
                                               u16* __restrict__ hout) {
    __shared__ __align__(16) u16 A_s[64 * 72];
    __shared__ __align__(16) u16 B_s[128 * 72];
    int tid = threadIdx.x;
    int lane = tid & 63, wid = tid >> 6;
    int wr = wid >> 1, wc = wid & 1;
    int l31 = lane & 31, lhi = lane >> 5;
    size_t rowBase = (size_t)blockIdx.y * 64;
    int cc = blockIdx.x * 128;

    f32x16 acc0 = {}, acc1 = {};
    int aoff = (wr * 32 + l31) * 72 + lhi * 8;
    int boff0 = (wc * 64 + l31) * 72 + lhi * 8;
    int boff1 = boff0 + 32 * 72;

    for (int sl = 0; sl < 10; ++sl) {
        int k0 = sl * 64;
        for (int idx = tid; idx < 512; idx += 256) {
            int m = idx >> 3, kv = idx & 7;
            int k = k0 + kv * 8;
            s16x8 v = {};
            if (k < HID) v = *(const s16x8*)&hid[(rowBase + m) * HID + k];
            *(s16x8*)&A_s[m * 72 + kv * 8] = v;
        }
        for (int idx = tid; idx < 1024; idx += 256) {
            int n = idx >> 3, kv = idx & 7;
            *(s16x8*)&B_s[n * 72 + kv * 8] =
                *(const s16x8*)&w2t[(size_t)(cc + n) * W2T_K + k0 + kv * 8];
        }
        __syncthreads();

        int smax = (sl < 9) ? 4 : 2;   // K = 608 total
        for (int s = 0; s < smax; ++s) {
            s16x8 a  = *(const s16x8*)&A_s[aoff + s * 16];
            s16x8 ba = *(const s16x8*)&B_s[boff0 + s * 16];
            s16x8 bb = *(const s16x8*)&B_s[boff1 + s * 16];
            acc0 = mfma_3216(a, ba, acc0);
            acc1 = mfma_3216(a, bb, acc1);
        }
        __syncthreads();
    }

    int colA = cc + wc * 64 + l31;
    int colB = colA + 32;
    if (colA < EMB) {
        float bias = b2[colA];
#pragma unroll
        for (int r = 0; r < 16; ++r) {
            int row = (r & 3) + 8 * (r >> 2) + 4 * lhi;
            hout[(rowBase + wr * 32 + row) * EMB + colA] = f2u(acc0[r] + bias);
        }
    }
    if (colB < EMB) {
        float bias = b2[colB];
#pragma unroll
        for (int r = 0; r < 16; ++r) {
            int row = (r & 3) + 8 * (r >> 2) + 4 * lhi;
            hout[(rowBase + wr * 32 + row) * EMB + colB] = f2u(acc1[r] + bias);
        }
    }
}

// ---------------- BN stats over bf16 matrix (u32-pair vectorized) ----------------
__global__ void k_bn_stats_h(const u16* __restrict__ X, float* __restrict__ stats) {
    int t = threadIdx.x;
    int half = t / 160;
    int pr = t - half * 160;
    if (pr >= 150) return;
    float s0 = 0.f, s1 = 0.f, q0 = 0.f, q1 = 0.f;
    for (int r = blockIdx.x * 2 + half; r < NN; r += 512) {
        u32 v = *(const u32*)&X[(size_t)r * EMB + pr * 2];
        float a = u2f((u16)(v & 0xffff));
        float b = u2f((u16)(v >> 16));
        s0 += a; s1 += b; q0 += a * a; q1 += b * b;
    }
    atomicAdd(&stats[2 * pr], s0);
    atomicAdd(&stats[2 * pr + 1], s1);
    atomicAdd(&stats[EMB + 2 * pr], q0);
    atomicAdd(&stats[EMB + 2 * pr + 1], q1);
}

template <bool RELU>
__global__ void k_bn_apply_h(u16* __restrict__ X, const float* __restrict__ stats,
                             const float* __restrict__ g, const float* __restrict__ b, float invM) {
    int r = blockIdx.x;
    for (int f = threadIdx.x; f < EMB; f += blockDim.x) {
        float mu = stats[f] * invM;
        float var = stats[EMB + f] * invM - mu * mu;
        float v = (u2f(X[(size_t)r * EMB + f]) - mu) * rsqrtf(var + 1e-5f) * g[f] + b[f];
        if (RELU) v = fmaxf(v, 0.f);
        X[(size_t)r * EMB + f] = f2u(v);
    }
}

// ---------------- BN stats / apply over fp32 (gate head) ----------------
__global__ void k_bn_stats_f(const float* __restrict__ X, int M, float* __restrict__ stats) {
    int f = threadIdx.x;
    if (f >= EMB) return;
    float s = 0.f, s2 = 0.f;
    for (int r = blockIdx.x; r < M; r += gridDim.x) {
        float v = X[(size_t)r * EMB + f];
        s += v;
        s2 += v * v;
    }
    atomicAdd(&stats[f], s);
    atomicAdd(&stats[EMB + f], s2);
}

template <bool RELU>
__global__ void k_bn_apply_f(float* __restrict__ X, const float* __restrict__ stats,
                             const float* __restrict__ g, const float* __restrict__ b, float invM) {
    int r = blockIdx.x;
    for (int f = threadIdx.x; f < EMB; f += blockDim.x) {
        float mu = stats[f] * invM;
        float var = stats[EMB + f] * invM - mu * mu;
        float v = (X[(size_t)r * EMB + f] - mu) * rsqrtf(var + 1e-5f) * g[f] + b[f];
        if (RELU) v = fmaxf(v, 0.f);
        X[(size_t)r * EMB + f] = v;
    }
}

// ---------------- fp32 tiled GEMM (gate head) ----------------
template <bool RELU>
__global__ __launch_bounds__(256) void k_gemm(const float* __restrict__ A,
                                              const float* __restrict__ B,
                                              const float* __restrict__ bias,
                                              float* __restrict__ C, int M, int N, int K) {
    __shared__ __align__(16) float As[16][68];
    __shared__ __align__(16) float Bs[16][68];
    int tid = threadIdx.x;
    int tx = tid & 15, ty = tid >> 4;
    int rowBase = blockIdx.y * 64;
    int colBase = blockIdx.x * 64;
    float acc[4][4] = {};
    for (int k0 = 0; k0 < K; k0 += 16) {
        for (int idx = tid; idx < 1024; idx += 256) {
            int m = idx >> 4, k = idx & 15;
            int gk = k0 + k;
            As[k][m] = (gk < K) ? A[(size_t)(rowBase + m) * K + gk] : 0.f;
        }
        for (int idx = tid; idx < 1024; idx += 256) {
            int kk = idx >> 6, n = idx & 63;
            int gk = k0 + kk, gn = colBase + n;
            Bs[kk][n] = (gk < K && gn < N) ? B[(size_t)gk * N + gn] : 0.f;
        }
        __syncthreads();
#pragma unroll
        for (int k = 0; k < 16; ++k) {
            const float* ar = &As[k][ty * 4];
            const float* br = &Bs[k][tx * 4];
            float a[4], b[4];
#pragma unroll
            for (int i = 0; i < 4; ++i) a[i] = ar[i];
#pragma unroll
            for (int j = 0; j < 4; ++j) b[j] = br[j];
#pragma unroll
            for (int i = 0; i < 4; ++i)
#pragma unroll
                for (int j = 0; j < 4; ++j) acc[i][j] += a[i] * b[j];
        }
        __syncthreads();
    }
#pragma unroll
    for (int i = 0; i < 4; ++i) {
        int r = rowBase + ty * 4 + i;
#pragma unroll
        for (int j = 0; j < 4; ++j) {
            int c = colBase + tx * 4 + j;
            if (c < N && r < M) {
                float v = acc[i][j] + bias[c];
                if (RELU) v = fmaxf(v, 0.f);
                C[(size_t)r * N + c] = v;
            }
        }
    }
}

// ---------------- graph pooling (batch sorted -> per-graph range, no atomics) ----------
__global__ void k_pool(const u16* __restrict__ h, const int* __restrict__ batch,
                       float* __restrict__ sums, float* __restrict__ counts) {
    __shared__ int range[2];
    int g = blockIdx.x;
    int t = threadIdx.x;
    if (t < 2) {
        int target = g + t;              // lower_bound(batch, target)
        int lo = 0, hi = NN;
        while (lo < hi) {
            int mid = (lo + hi) >> 1;
            if (batch[mid] < target) lo = mid + 1; else hi = mid;
        }
        range[t] = lo;
    }
    __syncthreads();
    int beg = range[0], end = range[1];
    if (t < EMB) {
        float s = 0.f;
        for (int r = beg; r < end; ++r) s += u2f(h[(size_t)r * EMB + t]);
        sums[(size_t)g * EMB + t] = s;
    }
    if (t == 0) counts[g] = (float)(end - beg);
}

// ---------------- clf_logit ----------------
__global__ void k_clf(const float* __restrict__ sums, const float* __restrict__ counts,
                      const float* __restrict__ ew, const float* __restrict__ eb,
                      float* __restrict__ out) {
    int gi = blockIdx.x;
    int t = threadIdx.x;
    if (t >= NTNE) return;
    float cnt = fmaxf(counts[gi], 1.f);
    float acc = 0.f;
    for (int k = 0; k < EMB; ++k) acc += sums[(size_t)gi * EMB + k] * ew[k * NTNE + t];
    out[(size_t)gi * NTNE + t] = acc / cnt + eb[t];
}

// ---------------- cluster norms ----------------
__global__ void k_cnorm(const float* __restrict__ cluster, float* __restrict__ cnorm) {
    int l = threadIdx.x;
    for (int e = 0; e < NEXP; ++e) {
        float s = 0.f;
        for (int f = l; f < EMB; f += 64) {
            float v = cluster[e * EMB + f];
            s += v * v;
        }
        for (int o = 32; o; o >>= 1) s += __shfl_xor(s, o);
        if (l == 0) cnorm[e] = sqrtf(s);
    }
}

// ---------------- z -> out ----------------
__global__ void k_zout(const float* __restrict__ z, float* __restrict__ out) {
    int gi = blockIdx.x;
    for (int f = threadIdx.x; f < EMB; f += blockDim.x)
        out[(size_t)gi * EMB + f] = z[(size_t)gi * EMB + f];
}

// ---------------- q = softmax(10 * zn @ cn^T) ----------------
__global__ void k_q(const float* __restrict__ z, const float* __restrict__ cluster,
                    const float* __restrict__ cnorm, float* __restrict__ qout) {
    int gi = blockIdx.x;
    int l = threadIdx.x;
    float s = 0.f;
    for (int f = l; f < EMB; f += 64) {
        float v = z[(size_t)gi * EMB + f];
        s += v * v;
    }
    for (int o = 32; o; o >>= 1) s += __shfl_xor(s, o);
    float zn = fmaxf(sqrtf(s), 1e-6f);
    float sc[NEXP];
#pragma unroll
    for (int e = 0; e < NEXP; ++e) {
        float d = 0.f;
        for (int f = l; f < EMB; f += 64) d += z[(size_t)gi * EMB + f] * cluster[e * EMB + f];
        for (int o = 32; o; o >>= 1) d += __shfl_xor(d, o);
        sc[e] = 10.f * d / (zn * fmaxf(cnorm[e], 1e-6f));
    }
    float mx = sc[0];
#pragma unroll
    for (int e = 1; e < NEXP; ++e) mx = fmaxf(mx, sc[e]);
    float se = 0.f;
#pragma unroll
    for (int e = 0; e < NEXP; ++e) {
        sc[e] = expf(sc[e] - mx);
        se += sc[e];
    }
    if (l < NEXP) qout[(size_t)gi * NEXP + l] = sc[l] / se;
}

extern "C" void kernel_launch(void* const* d_in, const int* in_sizes, int n_in,
                              void* d_out, int out_size, void* d_ws, size_t ws_size,
                              hipStream_t stream) {
    const int* x       = (const int*)d_in[0];
    const int* ei      = (const int*)d_in[1];
    const int* ea      = (const int*)d_in[2];
    const int* batch   = (const int*)d_in[3];
    const float* ae1   = (const float*)d_in[4];
    const float* ae2   = (const float*)d_in[5];
    const float* ee1   = (const float*)d_in[6];
    const float* ee2   = (const float*)d_in[7];
    const float* w1    = (const float*)d_in[8];
    const float* b1    = (const float*)d_in[9];
    const float* w2    = (const float*)d_in[10];
    const float* b2    = (const float*)d_in[11];
    const float* bng   = (const float*)d_in[12];
    const float* bnb   = (const float*)d_in[13];
    const float* gw1   = (const float*)d_in[14];
    const float* gb1   = (const float*)d_in[15];
    const float* gbng  = (const float*)d_in[16];
    const float* gbnb  = (const float*)d_in[17];
    const float* gw2   = (const float*)d_in[18];
    const float* gb2   = (const float*)d_in[19];
    const float* clus  = (const float*)d_in[20];
    const float* ew    = (const float*)d_in[21];
    const float* eb    = (const float*)d_in[22];

    // ---- workspace layout (~243 MiB) ----
    char* wp = (char*)d_ws;
    u16* hbuf = (u16*)wp;                 wp += (size_t)NN * EMB * sizeof(u16);   // 78.6 MB
    u16* hid = (u16*)wp;                  wp += (size_t)NN * HID * sizeof(u16);   // 157.3 MB
    float* stats = (float*)wp;            wp += 2 * EMB * sizeof(float);
    u16* w1t = (u16*)wp;                  wp += (size_t)NL * W1T_ROWS * W1T_K * sizeof(u16); // 2.1 MB
    u16* w2t = (u16*)wp;                  wp += (size_t)NL * W2T_ROWS * W2T_K * sizeof(u16); // 2.5 MB
    u16* eeT = (u16*)wp;                  wp += (size_t)NL * 18 * EE_S * sizeof(u16);        // 54.7 KB
    u16* scT = (u16*)wp;                  wp += EE_S * sizeof(u16);
    u16* shT = (u16*)wp;                  wp += EE_S * sizeof(u16);
    int* deg = (int*)wp;                  wp += (size_t)NN * sizeof(int);
    int* rowstart = (int*)wp;             wp += (size_t)(NN + 4) * sizeof(int);
    u32* payload = (u32*)wp;              wp += (size_t)NE * sizeof(u32);

    float* sums   = (float*)hid;   // post-loop overlays (hid dead)
    float* counts = sums + (size_t)NG * EMB;
    float* zh     = counts + NG;
    float* zb     = zh + (size_t)NG * EMB;
    float* cnorm  = zb + (size_t)NG * EMB;

    float* out     = (float*)d_out;
    float* out_clf = out;                       // NG*96
    float* out_z   = out + (size_t)NG * NTNE;   // NG*300
    float* out_q   = out_z + (size_t)NG * EMB;  // NG*8

    // CSR build (once per call)
    k_zero_int<<<NN / 256, 256, 0, stream>>>(deg, NN);
    k_hist<<<NE / 256, 256, 0, stream>>>(ei, deg);
    k_scan<<<1, 1024, 0, stream>>>(deg, rowstart);
    k_fill<<<NE / 256, 256, 0, stream>>>(ei, ea, deg, rowstart, payload);

    k_prep_w1<<<dim3(W1T_ROWS, NL), 64, 0, stream>>>(w1, w1t);
    k_prep_w2<<<dim3(W2T_ROWS, NL), 64, 0, stream>>>(w2, w2t);
    k_prep_ee<<<dim3(18, NL), 128, 0, stream>>>(ee1, ee2, eeT);
    k_embed<<<NN, 320, 0, stream>>>(x, ae1, ae2, hbuf);

    for (int l = 0; l < NL; ++l) {
        const u16* eeL = eeT + (size_t)l * 18 * EE_S;
        if (l == 0)
            k_layer1<false><<<NN / 32, 256, 0, stream>>>(
                hbuf, payload, rowstart, eeL, nullptr, nullptr,
                w1t + (size_t)l * W1T_ROWS * W1T_K, b1 + (size_t)l * HID, hid);
        else
            k_layer1<true><<<NN / 32, 256, 0, stream>>>(
                hbuf, payload, rowstart, eeL, scT, shT,
                w1t + (size_t)l * W1T_ROWS * W1T_K, b1 + (size_t)l * HID, hid);
        k_gemm2<<<dim3(3, NN / 64), 256, 0, stream>>>(hid, w2t + (size_t)l * W2T_ROWS * W2T_K,
                                                      b2 + (size_t)l * EMB, hbuf);
        k_zero<<<3, 256, 0, stream>>>(stats, 2 * EMB);
        k_bn_stats_h<<<256, 320, 0, stream>>>(hbuf, stats);
        if (l < NL - 1)
            k_prep_bn<<<1, 320, 0, stream>>>(stats, bng + (size_t)l * EMB,
                                             bnb + (size_t)l * EMB, 1.f / NN, scT, shT);
    }

    // final BN (no relu) materialized for pooling
    k_bn_apply_h<false><<<NN, 320, 0, stream>>>(hbuf, stats, bng + (size_t)(NL - 1) * EMB,
                                                bnb + (size_t)(NL - 1) * EMB, 1.f / NN);

    k_pool<<<NG, 320, 0, stream>>>(hbuf, batch, sums, counts);
    k_clf<<<NG, 128, 0, stream>>>(sums, counts, ew, eb, out_clf);

    // gate head
    k_gemm<false><<<dim3(5, NG / 64), 256, 0, stream>>>(sums, gw1, gb1, zh, NG, EMB, EMB);
    k_zero<<<3, 256, 0, stream>>>(stats, 2 * EMB);
    k_bn_stats_f<<<256, 320, 0, stream>>>(zh, NG, stats);
    k_bn_apply_f<true><<<NG, 320, 0, stream>>>(zh, stats, gbng, gbnb, 1.f / NG);
    k_gemm<false><<<dim3(5, NG / 64), 256, 0, stream>>>(zh, gw2, gb2, zb, NG, EMB, EMB);

    k_cnorm<<<1, 64, 0, stream>>>(clus, cnorm);
    k_zout<<<NG, 320, 0, stream>>>(zb, out_z);
    k_q<<<NG, 64, 0, stream>>>(zb, clus, cnorm, out_q);
}

// Round 19
// 3005.104 us; speedup vs baseline: 1.5282x; 1.5282x over previous
//
#include <hip/hip_runtime.h>
#include <hip/hip_bf16.h>

typedef unsigned short u16;
typedef unsigned int u32;

#define NN 131072   // nodes
#define NE 262144   // edges
#define NG 4096     // graphs
#define EMB 300
#define HID 600
#define NL 5
#define NTNE 96     // N_TASKS * N_EXPERTS
#define NEXP 8

// weight-transpose layouts (k-contiguous, padded)
#define W1T_ROWS 640
#define W1T_K    328
#define W2T_ROWS 384
#define W2T_K    648
#define EE_S     304   // ee table row stride (u16)

typedef __attribute__((ext_vector_type(8)))  short  s16x8;
typedef __attribute__((ext_vector_type(8)))  __bf16 b16x8;
typedef __attribute__((ext_vector_type(16))) float  f32x16;

static __device__ __forceinline__ float u2f(u16 u) {
    union { u32 i; float f; } w; w.i = ((u32)u) << 16; return w.f;
}
static __device__ __forceinline__ u16 f2u(float f) {
    union { float f; u32 i; } w; w.f = f;
    return (u16)((w.i + 0x7fffu + ((w.i >> 16) & 1u)) >> 16);
}

static __device__ __forceinline__ f32x16 mfma_3216(s16x8 a, s16x8 b, f32x16 c) {
    return __builtin_amdgcn_mfma_f32_32x32x16_bf16(
        __builtin_bit_cast(b16x8, a), __builtin_bit_cast(b16x8, b), c, 0, 0, 0);
}

// ---------------- zero fill ----------------
__global__ void k_zero(float* __restrict__ p, int n) {
    int i = blockIdx.x * 256 + threadIdx.x;
    if (i < n) p[i] = 0.f;
}
__global__ void k_zero_int(int* __restrict__ p, int n) {
    int i = blockIdx.x * 256 + threadIdx.x;
    if (i < n) p[i] = 0;
}

// ---------------- embedding ----------------
__global__ void k_embed(const int* __restrict__ x, const float* __restrict__ ae1,
                        const float* __restrict__ ae2, u16* __restrict__ h) {
    int i = blockIdx.x;
    int a0 = x[2 * i], a1 = x[2 * i + 1];
    for (int f = threadIdx.x; f < EMB; f += blockDim.x)
        h[(size_t)i * EMB + f] = f2u(ae1[a0 * EMB + f] + ae2[a1 * EMB + f]);
}

// ---------------- CSR build ----------------
__global__ void k_hist(const int* __restrict__ ei, int* __restrict__ deg) {
    int e = blockIdx.x * 256 + threadIdx.x;
    if (e < NE) atomicAdd(&deg[ei[NE + e]], 1);
}

__global__ __launch_bounds__(1024) void k_scan(const int* __restrict__ deg,
                                               int* __restrict__ rowstart) {
    __shared__ int lds[1024];
    int tid = threadIdx.x;
    int base = tid * 128;   // 1024 * 128 = 131072
    int s = 0;
    for (int j = 0; j < 128; ++j) s += deg[base + j];
    lds[tid] = s;
    __syncthreads();
    for (int off = 1; off < 1024; off <<= 1) {
        int v = (tid >= off) ? lds[tid - off] : 0;
        __syncthreads();
        lds[tid] += v;
        __syncthreads();
    }
    int run = (tid == 0) ? 0 : lds[tid - 1];
    for (int j = 0; j < 128; ++j) {
        rowstart[base + j] = run;
        run += deg[base + j];
    }
    if (tid == 1023) rowstart[NN] = run;
}

// consumes deg as cursor (ends at 0). payload = src | combo<<17, combo = b0*3+b1
__global__ void k_fill(const int* __restrict__ ei, const int* __restrict__ ea,
                       int* __restrict__ deg, const int* __restrict__ rowstart,
                       u32* __restrict__ payload) {
    int e = blockIdx.x * 256 + threadIdx.x;
    if (e >= NE) return;
    int src = ei[e], dst = ei[NE + e];
    int c = ea[2 * e] * 3 + ea[2 * e + 1];
    int old = atomicSub(&deg[dst], 1);
    int pos = rowstart[dst] + old - 1;
    payload[pos] = (u32)src | ((u32)c << 17);
}

// ---------------- weight pre-transpose (fp32 -> bf16, k-contiguous) ----------------
__global__ void k_prep_w1(const float* __restrict__ w1, u16* __restrict__ w1t) {
    int n = blockIdx.x;
    int l = blockIdx.y;
    size_t dst = ((size_t)l * W1T_ROWS + n) * W1T_K;
    for (int k = threadIdx.x; k < W1T_K; k += blockDim.x) {
        u16 v = 0;
        if (n < HID && k < EMB) v = f2u(w1[(size_t)l * EMB * HID + (size_t)k * HID + n]);
        w1t[dst + k] = v;
    }
}
__global__ void k_prep_w2(const float* __restrict__ w2, u16* __restrict__ w2t) {
    int n = blockIdx.x;
    int l = blockIdx.y;
    size_t dst = ((size_t)l * W2T_ROWS + n) * W2T_K;
    for (int k = threadIdx.x; k < W2T_K; k += blockDim.x) {
        u16 v = 0;
        if (n < EMB && k < HID) v = f2u(w2[(size_t)l * HID * EMB + (size_t)k * EMB + n]);
        w2t[dst + k] = v;
    }
}

// ---------------- ee-combo table (bf16), once per call ----------------
__global__ void k_prep_ee(const float* __restrict__ ee1, const float* __restrict__ ee2,
                          u16* __restrict__ eeT) {
    int c = blockIdx.x;   // 0..17
    int l = blockIdx.y;   // layer
    size_t dst = ((size_t)l * 18 + c) * EE_S;
    const float* e1 = ee1 + (size_t)l * 6 * EMB + (c / 3) * EMB;
    const float* e2 = ee2 + (size_t)l * 3 * EMB + (c % 3) * EMB;
    for (int f = threadIdx.x; f < EE_S; f += blockDim.x)
        eeT[dst + f] = (f < EMB) ? f2u(e1[f] + e2[f]) : (u16)0;
}

// ---------------- BN scale/shift table (bf16), per layer ----------------
__global__ void k_prep_bn(const float* __restrict__ stats, const float* __restrict__ bg,
                          const float* __restrict__ bb, float invM,
                          u16* __restrict__ scT, u16* __restrict__ shT) {
    int t = threadIdx.x;
    if (t >= EE_S) return;
    if (t < EMB) {
        float mu = stats[t] * invM;
        float var = stats[EMB + t] * invM - mu * mu;
        float sc = bg[t] * rsqrtf(var + 1e-5f);
        scT[t] = f2u(sc);
        shT[t] = f2u(bb[t] - mu * sc);
    } else {
        scT[t] = 0; shT[t] = 0;
    }
}

// ---- fused (BN+relu of prev layer) + aggregate + GEMM1: hid = relu(A @ W1 + b1) ----
// Row-pair gather: each task handles rows pr and pr+32 with jointly-iterated edge
// loops (2 independent miss chains). ee/scale/shift from L1-resident global tables.
// LDS = A_s only (41 KB) -> 3 blocks/CU.
template <bool APPLY_BN>
__global__ __launch_bounds__(512) void k_layer1(const u16* __restrict__ h,
                                                const u32* __restrict__ payload,
                                                const int* __restrict__ rowstart,
                                                const u16* __restrict__ eeT,
                                                const u16* __restrict__ scT,
                                                const u16* __restrict__ shT,
                                                const u16* __restrict__ w1t,
                                                const float* __restrict__ b1,
                                                u16* __restrict__ hid) {
    __shared__ __align__(16) u16 A_s[64 * 328];       // 41 KB
    int tid = threadIdx.x;
    int lane = tid & 63, wid = tid >> 6;
    int wr = wid >> 2, wc = wid & 3;
    int l31 = lane & 31, lhi = lane >> 5;
    size_t rowBase = (size_t)blockIdx.x * 64;

    for (int idx = tid; idx < 64 * 28; idx += 512)
        A_s[(idx / 28) * 328 + 300 + (idx % 28)] = 0;
    __syncthreads();

    // gather: 32 row-pairs x 75 feature-chunks
    for (int task = tid; task < 32 * 75; task += 512) {
        int pr = task / 75, fc = task - pr * 75;
        int f0 = fc * 4;
        int iA = (int)rowBase + pr;
        int iB = iA + 32;
        int begA = rowstart[iA], endA = rowstart[iA + 1];
        int begB = rowstart[iB], endB = rowstart[iB + 1];
        float sc0 = 1.f, sc1 = 1.f, sc2 = 1.f, sc3 = 1.f;
        float sh0 = 0.f, sh1 = 0.f, sh2 = 0.f, sh3 = 0.f;
        if (APPLY_BN) {
            ushort4 scv = *(const ushort4*)&scT[f0];
            ushort4 shv = *(const ushort4*)&shT[f0];
            sc0 = u2f(scv.x); sc1 = u2f(scv.y); sc2 = u2f(scv.z); sc3 = u2f(scv.w);
            sh0 = u2f(shv.x); sh1 = u2f(shv.y); sh2 = u2f(shv.z); sh3 = u2f(shv.w);
        }
        ushort4 ev = *(const ushort4*)&eeT[12 * EE_S + f0];  // self combo
        float e0 = u2f(ev.x), e1v = u2f(ev.y), e2v = u2f(ev.z), e3 = u2f(ev.w);

        ushort4 hvA = *(const ushort4*)&h[(size_t)iA * EMB + f0];
        ushort4 hvB = *(const ushort4*)&h[(size_t)iB * EMB + f0];
        float vA0 = u2f(hvA.x), vA1 = u2f(hvA.y), vA2 = u2f(hvA.z), vA3 = u2f(hvA.w);
        float vB0 = u2f(hvB.x), vB1 = u2f(hvB.y), vB2 = u2f(hvB.z), vB3 = u2f(hvB.w);
        if (APPLY_BN) {
            vA0 = fmaxf(vA0 * sc0 + sh0, 0.f); vB0 = fmaxf(vB0 * sc0 + sh0, 0.f);
            vA1 = fmaxf(vA1 * sc1 + sh1, 0.f); vB1 = fmaxf(vB1 * sc1 + sh1, 0.f);
            vA2 = fmaxf(vA2 * sc2 + sh2, 0.f); vB2 = fmaxf(vB2 * sc2 + sh2, 0.f);
            vA3 = fmaxf(vA3 * sc3 + sh3, 0.f); vB3 = fmaxf(vB3 * sc3 + sh3, 0.f);
        }
        vA0 += e0; vA1 += e1v; vA2 += e2v; vA3 += e3;
        vB0 += e0; vB1 += e1v; vB2 += e2v; vB3 += e3;

        int eA = begA, eB = begB;
        // joint loop: two independent miss chains in flight
        while (eA < endA && eB < endB) {
            u32 pA = payload[eA], pB = payload[eB];
            int sA = pA & 0x1FFFF, sB = pB & 0x1FFFF;
            ushort4 svA = *(const ushort4*)&h[(size_t)sA * EMB + f0];
            ushort4 svB = *(const ushort4*)&h[(size_t)sB * EMB + f0];
            ushort4 ecA = *(const ushort4*)&eeT[(size_t)(pA >> 17) * EE_S + f0];
            ushort4 ecB = *(const ushort4*)&eeT[(size_t)(pB >> 17) * EE_S + f0];
            float gA0 = u2f(svA.x), gA1 = u2f(svA.y), gA2 = u2f(svA.z), gA3 = u2f(svA.w);
            float gB0 = u2f(svB.x), gB1 = u2f(svB.y), gB2 = u2f(svB.z), gB3 = u2f(svB.w);
            if (APPLY_BN) {
                gA0 = fmaxf(gA0 * sc0 + sh0, 0.f); gB0 = fmaxf(gB0 * sc0 + sh0, 0.f);
                gA1 = fmaxf(gA1 * sc1 + sh1, 0.f); gB1 = fmaxf(gB1 * sc1 + sh1, 0.f);
                gA2 = fmaxf(gA2 * sc2 + sh2, 0.f); gB2 = fmaxf(gB2 * sc2 + sh2, 0.f);
                gA3 = fmaxf(gA3 * sc3 + sh3, 0.f); gB3 = fmaxf(gB3 * sc3 + sh3, 0.f);
            }
            vA0 += gA0 + u2f(ecA.x); vB0 += gB0 + u2f(ecB.x);
            vA1 += gA1 + u2f(ecA.y); vB1 += gB1 + u2f(ecB.y);
            vA2 += gA2 + u2f(ecA.z); vB2 += gB2 + u2f(ecB.z);
            vA3 += gA3 + u2f(ecA.w); vB3 += gB3 + u2f(ecB.w);
            ++eA; ++eB;
        }
        for (; eA < endA; ++eA) {
            u32 p = payload[eA];
            int src = p & 0x1FFFF;
            ushort4 sv = *(const ushort4*)&h[(size_t)src * EMB + f0];
            ushort4 ec = *(const ushort4*)&eeT[(size_t)(p >> 17) * EE_S + f0];
            float g0 = u2f(sv.x), g1 = u2f(sv.y), g2 = u2f(sv.z), g3 = u2f(sv.w);
            if (APPLY_BN) {
                g0 = fmaxf(g0 * sc0 + sh0, 0.f);
                g1 = fmaxf(g1 * sc1 + sh1, 0.f);
                g2 = fmaxf(g2 * sc2 + sh2, 0.f);
                g3 = fmaxf(g3 * sc3 + sh3, 0.f);
            }
            vA0 += g0 + u2f(ec.x);
            vA1 += g1 + u2f(ec.y);
            vA2 += g2 + u2f(ec.z);
            vA3 += g3 + u2f(ec.w);
        }
        for (; eB < endB; ++eB) {
            u32 p = payload[eB];
            int src = p & 0x1FFFF;
            ushort4 sv = *(const ushort4*)&h[(size_t)src * EMB + f0];
            ushort4 ec = *(const ushort4*)&eeT[(size_t)(p >> 17) * EE_S + f0];
            float g0 = u2f(sv.x), g1 = u2f(sv.y), g2 = u2f(sv.z), g3 = u2f(sv.w);
            if (APPLY_BN) {
                g0 = fmaxf(g0 * sc0 + sh0, 0.f);
                g1 = fmaxf(g1 * sc1 + sh1, 0.f);
                g2 = fmaxf(g2 * sc2 + sh2, 0.f);
                g3 = fmaxf(g3 * sc3 + sh3, 0.f);
            }
            vB0 += g0 + u2f(ec.x);
            vB1 += g1 + u2f(ec.y);
            vB2 += g2 + u2f(ec.z);
            vB3 += g3 + u2f(ec.w);
        }
        short4 oA, oB;
        oA.x = (short)f2u(vA0); oA.y = (short)f2u(vA1);
        oA.z = (short)f2u(vA2); oA.w = (short)f2u(vA3);
        oB.x = (short)f2u(vB0); oB.y = (short)f2u(vB1);
        oB.z = (short)f2u(vB2); oB.w = (short)f2u(vB3);
        *(short4*)&A_s[pr * 328 + f0] = oA;
        *(short4*)&A_s[(pr + 32) * 328 + f0] = oB;
    }
    __syncthreads();

    // preload all A fragments (20 ksteps)
    s16x8 afr[20];
    int abase = (wr * 32 + l31) * 328 + lhi * 8;
#pragma unroll
    for (int s = 0; s < 20; ++s) afr[s] = *(const s16x8*)&A_s[abase + s * 16];

    // 5 col-chunks of 128; B direct from w1t (L2)
    for (int c5 = 0; c5 < 5; ++c5) {
        int col = c5 * 128 + wc * 32 + l31;
        const u16* bp = w1t + (size_t)col * W1T_K + lhi * 8;
        f32x16 acc = {};
#pragma unroll
        for (int s = 0; s < 20; ++s)
            acc = mfma_3216(afr[s], *(const s16x8*)&bp[s * 16], acc);
        if (col < HID) {
            float bias = b1[col];
#pragma unroll
            for (int r = 0; r < 16; ++r) {
                int row = (r & 3) + 8 * (r >> 2) + 4 * lhi;
                hid[(rowBase + wr * 32 + row) * HID + col] =
                    f2u(fmaxf(acc[r] + bias, 0.f));
            }
        }
    }
}

// ---------------- MFMA GEMM2 (LDS-staged, k-tiled): hbuf = hid @ W2 + b2 --------
// grid (NN/64, 3), 256 threads = 4 waves (2 row x 2 col), wave tile 32x64. 27.6 KB LDS.
__global__ __launch_bounds__(256) void k_gemm2(const u16* __restrict__ hid,
                                               const u16* __restrict__ w2t,
                                               const float* __restrict__ b2,
                                               u16* __restrict__ hout) {
    __shared__ __align__(16) u16 A_s[64 * 72];
    __shared__ __align__(16) u16 B_s[128 * 72];
    int tid = threadIdx.x;
    int lane = tid & 63, wid = tid >> 6;
    int wr = wid >> 1, wc = wid & 1;
    int l31 = lane & 31, lhi = lane >> 5;
    size_t rowBase = (size_t)blockIdx.x * 64;
    int cc = blockIdx.y * 128;

    f32x16 acc0 = {}, acc1 = {};
    int aoff = (wr * 32 + l31) * 72 + lhi * 8;
    int boff0 = (wc * 64 + l31) * 72 + lhi * 8;
    int boff1 = boff0 + 32 * 72;

    for (int sl = 0; sl < 10; ++sl) {
        int k0 = sl * 64;
        for (int idx = tid; idx < 512; idx += 256) {
            int m = idx >> 3, kv = idx & 7;
            int k = k0 + kv * 8;
            s16x8 v = {};
            if (k < HID) v = *(const s16x8*)&hid[(rowBase + m) * HID + k];
            *(s16x8*)&A_s[m * 72 + kv * 8] = v;
        }
        for (int idx = tid; idx < 1024; idx += 256) {
            int n = idx >> 3, kv = idx & 7;
            *(s16x8*)&B_s[n * 72 + kv * 8] =
                *(const s16x8*)&w2t[(size_t)(cc + n) * W2T_K + k0 + kv * 8];
        }
        __syncthreads();

        int smax = (sl < 9) ? 4 : 2;   // K = 608 total
        for (int s = 0; s < smax; ++s) {
            s16x8 a  = *(const s16x8*)&A_s[aoff + s * 16];
            s16x8 ba = *(const s16x8*)&B_s[boff0 + s * 16];
            s16x8 bb = *(const s16x8*)&B_s[boff1 + s * 16];
            acc0 = mfma_3216(a, ba, acc0);
            acc1 = mfma_3216(a, bb, acc1);
        }
        __syncthreads();
    }

    int colA = cc + wc * 64 + l31;
    int colB = colA + 32;
    if (colA < EMB) {
        float bias = b2[colA];
#pragma unroll
        for (int r = 0; r < 16; ++r) {
            int row = (r & 3) + 8 * (r >> 2) + 4 * lhi;
            hout[(rowBase + wr * 32 + row) * EMB + colA] = f2u(acc0[r] + bias);
        }
    }
    if (colB < EMB) {
        float bias = b2[colB];
#pragma unroll
        for (int r = 0; r < 16; ++r) {
            int row = (r & 3) + 8 * (r >> 2) + 4 * lhi;
            hout[(rowBase + wr * 32 + row) * EMB + colB] = f2u(acc1[r] + bias);
        }
    }
}

// ---------------- BN stats over bf16 matrix (u32-pair vectorized) ----------------
__global__ void k_bn_stats_h(const u16* __restrict__ X, float* __restrict__ stats) {
    int t = threadIdx.x;
    int half = t / 160;
    int pr = t - half * 160;
    if (pr >= 150) return;
    float s0 = 0.f, s1 = 0.f, q0 = 0.f, q1 = 0.f;
    for (int r = blockIdx.x * 2 + half; r < NN; r += 512) {
        u32 v = *(const u32*)&X[(size_t)r * EMB + pr * 2];
        float a = u2f((u16)(v & 0xffff));
        float b = u2f((u16)(v >> 16));
        s0 += a; s1 += b; q0 += a * a; q1 += b * b;
    }
    atomicAdd(&stats[2 * pr], s0);
    atomicAdd(&stats[2 * pr + 1], s1);
    atomicAdd(&stats[EMB + 2 * pr], q0);
    atomicAdd(&stats[EMB + 2 * pr + 1], q1);
}

template <bool RELU>
__global__ void k_bn_apply_h(u16* __restrict__ X, const float* __restrict__ stats,
                             const float* __restrict__ g, const float* __restrict__ b, float invM) {
    int r = blockIdx.x;
    for (int f = threadIdx.x; f < EMB; f += blockDim.x) {
        float mu = stats[f] * invM;
        float var = stats[EMB + f] * invM - mu * mu;
        float v = (u2f(X[(size_t)r * EMB + f]) - mu) * rsqrtf(var + 1e-5f) * g[f] + b[f];
        if (RELU) v = fmaxf(v, 0.f);
        X[(size_t)r * EMB + f] = f2u(v);
    }
}

// ---------------- BN stats / apply over fp32 (gate head) ----------------
__global__ void k_bn_stats_f(const float* __restrict__ X, int M, float* __restrict__ stats) {
    int f = threadIdx.x;
    if (f >= EMB) return;
    float s = 0.f, s2 = 0.f;
    for (int r = blockIdx.x; r < M; r += gridDim.x) {
        float v = X[(size_t)r * EMB + f];
        s += v;
        s2 += v * v;
    }
    atomicAdd(&stats[f], s);
    atomicAdd(&stats[EMB + f], s2);
}

template <bool RELU>
__global__ void k_bn_apply_f(float* __restrict__ X, const float* __restrict__ stats,
                             const float* __restrict__ g, const float* __restrict__ b, float invM) {
    int r = blockIdx.x;
    for (int f = threadIdx.x; f < EMB; f += blockDim.x) {
        float mu = stats[f] * invM;
        float var = stats[EMB + f] * invM - mu * mu;
        float v = (X[(size_t)r * EMB + f] - mu) * rsqrtf(var + 1e-5f) * g[f] + b[f];
        if (RELU) v = fmaxf(v, 0.f);
        X[(size_t)r * EMB + f] = v;
    }
}

// ---------------- fp32 tiled GEMM (gate head) ----------------
template <bool RELU>
__global__ __launch_bounds__(256) void k_gemm(const float* __restrict__ A,
                                              const float* __restrict__ B,
                                              const float* __restrict__ bias,
                                              float* __restrict__ C, int M, int N, int K) {
    __shared__ __align__(16) float As[16][68];
    __shared__ __align__(16) float Bs[16][68];
    int tid = threadIdx.x;
    int tx = tid & 15, ty = tid >> 4;
    int rowBase = blockIdx.y * 64;
    int colBase = blockIdx.x * 64;
    float acc[4][4] = {};
    for (int k0 = 0; k0 < K; k0 += 16) {
        for (int idx = tid; idx < 1024; idx += 256) {
            int m = idx >> 4, k = idx & 15;
            int gk = k0 + k;
            As[k][m] = (gk < K) ? A[(size_t)(rowBase + m) * K + gk] : 0.f;
        }
        for (int idx = tid; idx < 1024; idx += 256) {
            int kk = idx >> 6, n = idx & 63;
            int gk = k0 + kk, gn = colBase + n;
            Bs[kk][n] = (gk < K && gn < N) ? B[(size_t)gk * N + gn] : 0.f;
        }
        __syncthreads();
#pragma unroll
        for (int k = 0; k < 16; ++k) {
            const float* ar = &As[k][ty * 4];
            const float* br = &Bs[k][tx * 4];
            float a[4], b[4];
#pragma unroll
            for (int i = 0; i < 4; ++i) a[i] = ar[i];
#pragma unroll
            for (int j = 0; j < 4; ++j) b[j] = br[j];
#pragma unroll
            for (int i = 0; i < 4; ++i)
#pragma unroll
                for (int j = 0; j < 4; ++j) acc[i][j] += a[i] * b[j];
        }
        __syncthreads();
    }
#pragma unroll
    for (int i = 0; i < 4; ++i) {
        int r = rowBase + ty * 4 + i;
#pragma unroll
        for (int j = 0; j < 4; ++j) {
            int c = colBase + tx * 4 + j;
            if (c < N && r < M) {
                float v = acc[i][j] + bias[c];
                if (RELU) v = fmaxf(v, 0.f);
                C[(size_t)r * N + c] = v;
            }
        }
    }
}

// ---------------- graph pooling (batch sorted -> per-graph range, no atomics) ----------
__global__ void k_pool(const u16* __restrict__ h, const int* __restrict__ batch,
                       float* __restrict__ sums, float* __restrict__ counts) {
    __shared__ int range[2];
    int g = blockIdx.x;
    int t = threadIdx.x;
    if (t < 2) {
        int target = g + t;              // lower_bound(batch, target)
        int lo = 0, hi = NN;
        while (lo < hi) {
            int mid = (lo + hi) >> 1;
            if (batch[mid] < target) lo = mid + 1; else hi = mid;
        }
        range[t] = lo;
    }
    __syncthreads();
    int beg = range[0], end = range[1];
    if (t < EMB) {
        float s = 0.f;
        for (int r = beg; r < end; ++r) s += u2f(h[(size_t)r * EMB + t]);
        sums[(size_t)g * EMB + t] = s;
    }
    if (t == 0) counts[g] = (float)(end - beg);
}

// ---------------- clf_logit ----------------
__global__ void k_clf(const float* __restrict__ sums, const float* __restrict__ counts,
                      const float* __restrict__ ew, const float* __restrict__ eb,
                      float* __restrict__ out) {
    int gi = blockIdx.x;
    int t = threadIdx.x;
    if (t >= NTNE) return;
    float cnt = fmaxf(counts[gi], 1.f);
    float acc = 0.f;
    for (int k = 0; k < EMB; ++k) acc += sums[(size_t)gi * EMB + k] * ew[k * NTNE + t];
    out[(size_t)gi * NTNE + t] = acc / cnt + eb[t];
}

// ---------------- cluster norms ----------------
__global__ void k_cnorm(const float* __restrict__ cluster, float* __restrict__ cnorm) {
    int l = threadIdx.x;
    for (int e = 0; e < NEXP; ++e) {
        float s = 0.f;
        for (int f = l; f < EMB; f += 64) {
            float v = cluster[e * EMB + f];
            s += v * v;
        }
        for (int o = 32; o; o >>= 1) s += __shfl_xor(s, o);
        if (l == 0) cnorm[e] = sqrtf(s);
    }
}

// ---------------- z -> out ----------------
__global__ void k_zout(const float* __restrict__ z, float* __restrict__ out) {
    int gi = blockIdx.x;
    for (int f = threadIdx.x; f < EMB; f += blockDim.x)
        out[(size_t)gi * EMB + f] = z[(size_t)gi * EMB + f];
}

// ---------------- q = softmax(10 * zn @ cn^T) ----------------
__global__ void k_q(const float* __restrict__ z, const float* __restrict__ cluster,
                    const float* __restrict__ cnorm, float* __restrict__ qout) {
    int gi = blockIdx.x;
    int l = threadIdx.x;
    float s = 0.f;
    for (int f = l; f < EMB; f += 64) {
        float v = z[(size_t)gi * EMB + f];
        s += v * v;
    }
    for (int o = 32; o; o >>= 1) s += __shfl_xor(s, o);
    float zn = fmaxf(sqrtf(s), 1e-6f);
    float sc[NEXP];
#pragma unroll
    for (int e = 0; e < NEXP; ++e) {
        float d = 0.f;
        for (int f = l; f < EMB; f += 64) d += z[(size_t)gi * EMB + f] * cluster[e * EMB + f];
        for (int o = 32; o; o >>= 1) d += __shfl_xor(d, o);
        sc[e] = 10.f * d / (zn * fmaxf(cnorm[e], 1e-6f));
    }
    float mx = sc[0];
#pragma unroll
    for (int e = 1; e < NEXP; ++e) mx = fmaxf(mx, sc[e]);
    float se = 0.f;
#pragma unroll
    for (int e = 0; e < NEXP; ++e) {
        sc[e] = expf(sc[e] - mx);
        se += sc[e];
    }
    if (l < NEXP) qout[(size_t)gi * NEXP + l] = sc[l] / se;
}

extern "C" void kernel_launch(void* const* d_in, const int* in_sizes, int n_in,
                              void* d_out, int out_size, void* d_ws, size_t ws_size,
                              hipStream_t stream) {
    const int* x       = (const int*)d_in[0];
    const int* ei      = (const int*)d_in[1];
    const int* ea      = (const int*)d_in[2];
    const int* batch   = (const int*)d_in[3];
    const float* ae1   = (const float*)d_in[4];
    const float* ae2   = (const float*)d_in[5];
    const float* ee1   = (const float*)d_in[6];
    const float* ee2   = (const float*)d_in[7];
    const float* w1    = (const float*)d_in[8];
    const float* b1    = (const float*)d_in[9];
    const float* w2    = (const float*)d_in[10];
    const float* b2    = (const float*)d_in[11];
    const float* bng   = (const float*)d_in[12];
    const float* bnb   = (const float*)d_in[13];
    const float* gw1   = (const float*)d_in[14];
    const float* gb1   = (const float*)d_in[15];
    const float* gbng  = (const float*)d_in[16];
    const float* gbnb  = (const float*)d_in[17];
    const float* gw2   = (const float*)d_in[18];
    const float* gb2   = (const float*)d_in[19];
    const float* clus  = (const float*)d_in[20];
    const float* ew    = (const float*)d_in[21];
    const float* eb    = (const float*)d_in[22];

    // ---- workspace layout (~243 MiB) ----
    char* wp = (char*)d_ws;
    u16* hbuf = (u16*)wp;                 wp += (size_t)NN * EMB * sizeof(u16);   // 78.6 MB
    u16* hid = (u16*)wp;                  wp += (size_t)NN * HID * sizeof(u16);   // 157.3 MB
    float* stats = (float*)wp;            wp += 2 * EMB * sizeof(float);
    u16* w1t = (u16*)wp;                  wp += (size_t)NL * W1T_ROWS * W1T_K * sizeof(u16); // 2.1 MB
    u16* w2t = (u16*)wp;                  wp += (size_t)NL * W2T_ROWS * W2T_K * sizeof(u16); // 2.5 MB
    u16* eeT = (u16*)wp;                  wp += (size_t)NL * 18 * EE_S * sizeof(u16);        // 54.7 KB
    u16* scT = (u16*)wp;                  wp += EE_S * sizeof(u16);
    u16* shT = (u16*)wp;                  wp += EE_S * sizeof(u16);
    int* deg = (int*)wp;                  wp += (size_t)NN * sizeof(int);
    int* rowstart = (int*)wp;             wp += (size_t)(NN + 4) * sizeof(int);
    u32* payload = (u32*)wp;              wp += (size_t)NE * sizeof(u32);

    float* sums   = (float*)hid;   // post-loop overlays (hid dead)
    float* counts = sums + (size_t)NG * EMB;
    float* zh     = counts + NG;
    float* zb     = zh + (size_t)NG * EMB;
    float* cnorm  = zb + (size_t)NG * EMB;

    float* out     = (float*)d_out;
    float* out_clf = out;                       // NG*96
    float* out_z   = out + (size_t)NG * NTNE;   // NG*300
    float* out_q   = out_z + (size_t)NG * EMB;  // NG*8

    // CSR build (once per call)
    k_zero_int<<<NN / 256, 256, 0, stream>>>(deg, NN);
    k_hist<<<NE / 256, 256, 0, stream>>>(ei, deg);
    k_scan<<<1, 1024, 0, stream>>>(deg, rowstart);
    k_fill<<<NE / 256, 256, 0, stream>>>(ei, ea, deg, rowstart, payload);

    k_prep_w1<<<dim3(W1T_ROWS, NL), 64, 0, stream>>>(w1, w1t);
    k_prep_w2<<<dim3(W2T_ROWS, NL), 64, 0, stream>>>(w2, w2t);
    k_prep_ee<<<dim3(18, NL), 128, 0, stream>>>(ee1, ee2, eeT);
    k_embed<<<NN, 320, 0, stream>>>(x, ae1, ae2, hbuf);

    for (int l = 0; l < NL; ++l) {
        const u16* eeL = eeT + (size_t)l * 18 * EE_S;
        if (l == 0)
            k_layer1<false><<<NN / 64, 512, 0, stream>>>(
                hbuf, payload, rowstart, eeL, nullptr, nullptr,
                w1t + (size_t)l * W1T_ROWS * W1T_K, b1 + (size_t)l * HID, hid);
        else
            k_layer1<true><<<NN / 64, 512, 0, stream>>>(
                hbuf, payload, rowstart, eeL, scT, shT,
                w1t + (size_t)l * W1T_ROWS * W1T_K, b1 + (size_t)l * HID, hid);
        k_gemm2<<<dim3(NN / 64, 3), 256, 0, stream>>>(hid, w2t + (size_t)l * W2T_ROWS * W2T_K,
                                                      b2 + (size_t)l * EMB, hbuf);
        k_zero<<<3, 256, 0, stream>>>(stats, 2 * EMB);
        k_bn_stats_h<<<256, 320, 0, stream>>>(hbuf, stats);
        if (l < NL - 1)
            k_prep_bn<<<1, 320, 0, stream>>>(stats, bng + (size_t)l * EMB,
                                             bnb + (size_t)l * EMB, 1.f / NN, scT, shT);
    }

    // final BN (no relu) materialized for pooling
    k_bn_apply_h<false><<<NN, 320, 0, stream>>>(hbuf, stats, bng + (size_t)(NL - 1) * EMB,
                                                bnb + (size_t)(NL - 1) * EMB, 1.f / NN);

    k_pool<<<NG, 320, 0, stream>>>(hbuf, batch, sums, counts);
    k_clf<<<NG, 128, 0, stream>>>(sums, counts, ew, eb, out_clf);

    // gate head
    k_gemm<false><<<dim3(5, NG / 64), 256, 0, stream>>>(sums, gw1, gb1, zh, NG, EMB, EMB);
    k_zero<<<3, 256, 0, stream>>>(stats, 2 * EMB);
    k_bn_stats_f<<<256, 320, 0, stream>>>(zh, NG, stats);
    k_bn_apply_f<true><<<NG, 320, 0, stream>>>(zh, stats, gbng, gbnb, 1.f / NG);
    k_gemm<false><<<dim3(5, NG / 64), 256, 0, stream>>>(zh, gw2, gb2, zb, NG, EMB, EMB);

    k_cnorm<<<1, 64, 0, stream>>>(clus, cnorm);
    k_zout<<<NG, 320, 0, stream>>>(zb, out_z);
    k_q<<<NG, 64, 0, stream>>>(zb, clus, cnorm, out_q);
}